// Round 7
// baseline (244.254 us; speedup 1.0000x reference)
//
#include <hip/hip_runtime.h>
#include <cstdint>

using u16 = unsigned short;
typedef short bf16x8 __attribute__((ext_vector_type(8)));
typedef float f32x4 __attribute__((ext_vector_type(4)));

__device__ __forceinline__ float bf2f(u16 h) {
    union { unsigned u; float f; } x;
    x.u = ((unsigned)h) << 16;
    return x.f;
}
__device__ __forceinline__ u16 f2bf(float f) {
    union { float f; unsigned u; } x;
    x.f = f;
    unsigned r = x.u + 0x7fffu + ((x.u >> 16) & 1u);
    return (u16)(r >> 16);
}

// async global->LDS, 16B per lane; LDS dest is wave-uniform base + lane*16
__device__ __forceinline__ void gl_lds16(const u16* g, u16* l) {
    __builtin_amdgcn_global_load_lds((const __attribute__((address_space(1))) void*)g,
                                     (__attribute__((address_space(3))) void*)l, 16, 0, 0);
}

#define N1 8192
#define N2 2048
#define C2 256

// ---------------------------------------------------------------------------
// preproc (R15): points2 transpose + w0/w1 cvt + stats zero.
// ---------------------------------------------------------------------------
__device__ __forceinline__ void tr_tile(const float* __restrict__ src,
                                        u16* __restrict__ dst,
                                        int C, int N, int ds, int b, int n0, int c0,
                                        int tid, float (*tile)[33]) {
    int tx = tid & 31, ty = tid >> 5;  // 32 x 8
    const float* s = src + (long)b * C * N;
#pragma unroll
    for (int i = 0; i < 4; i++) {
        int c = ty + i * 8;
        tile[c][tx] = s[(long)(c0 + c) * N + n0 + tx];
    }
    __syncthreads();
    u16* d = dst + (long)b * N * ds;
#pragma unroll
    for (int i = 0; i < 4; i++) {
        int n = ty + i * 8;
        d[(long)(n0 + n) * ds + c0 + tx] = f2bf(tile[tx][n]);
    }
}

__global__ __launch_bounds__(256) void preproc(const float* __restrict__ w0,
                                               const float* __restrict__ w1,
                                               const float* __restrict__ points2,
                                               u16* __restrict__ w0b,
                                               u16* __restrict__ w1b,
                                               u16* __restrict__ P2T,
                                               float* __restrict__ stats) {
    __shared__ float tile[32][33];
    int bid = blockIdx.x, tid = threadIdx.x;
    if (bid < 4096) {
        int nb = bid & 63, cb = (bid >> 6) & 7, b = bid >> 9;
        tr_tile(points2, P2T, 256, 2048, 256, b, nb * 32, cb * 32, tid, tile);
    } else if (bid < 4480) {
        int i = (bid - 4096) * 256 + tid;
        w0b[i] = f2bf(w0[i]);
    } else if (bid < 4608) {
        int i = (bid - 4480) * 256 + tid;
        w1b[i] = f2bf(w1[i]);
    } else {
        for (int i = tid; i < 768; i += 256) stats[i] = 0.0f;
    }
}

// ---------------------------------------------------------------------------
// kNN(3) + interpolation — R16: scan/merge/gather = R9 VERBATIM (frozen).
// Fused points1->X copy, v2. R15 post-mortem: VGPR=24 proved the compiler
// SANK the 16 float loads to the store site (latency exposed at the end),
// and the store phase was 8x scattered 4B dwords (64-sector transactions).
// Fixes: (a) asm-keep right after the scan forces the loads live across it
// (issue early, complete under ~70us of VALU work); (b) reuse pts LDS
// (dead after scan) as a 64x64-u32 tile: ds_write channel pairs, barrier,
// then fully-coalesced 32B/thread dwordx4 stores (256B/row).
// ---------------------------------------------------------------------------
__global__ __launch_bounds__(512) void knn_interp(const float* __restrict__ xyz1,
                                                  const float* __restrict__ xyz2,
                                                  const float* __restrict__ points1,
                                                  const u16* __restrict__ P2T,  // [B][N2][C2]
                                                  u16* __restrict__ X) {       // [B*N1][384]
    __shared__ float4 pts[N2 / 2];      // 16384 B (half-staged; reused as p1 tile)
    __shared__ float m_d[8][64][3];     // 6144 B partial top-3 (squared dist)
    __shared__ int   m_i[8][64][3];     // 6144 B
    __shared__ int   s_idx[64][3];
    __shared__ float s_w[64][3];
    int b = blockIdx.y;
    int n0 = blockIdx.x * 64;
    int tid = threadIdx.x;
    int ql = tid & 63;       // query within block
    int part = tid >> 6;     // candidate partition 0..7 (== wave id)

    // ---- fused points1 copy: issue loads now; asm-keep after scan pins
    // them live so latency hides under the VALU-bound scan.
    int cp = tid >> 3;       // channel pair: channels 2cp, 2cp+1
    int g = tid & 7;         // n-octet within the 64-query tile
    const float* p1r0 = points1 + ((long)b * 128 + 2 * cp) * N1 + n0 + g * 8;
    const float* p1r1 = p1r0 + N1;
    float4 c0a = *(const float4*)(p1r0);
    float4 c0b = *(const float4*)(p1r0 + 4);
    float4 c1a = *(const float4*)(p1r1);
    float4 c1b = *(const float4*)(p1r1 + 4);

    int n = n0 + ql;
    float px = xyz1[((long)b * N1 + n) * 3 + 0];
    float py = xyz1[((long)b * N1 + n) * 3 + 1];
    float pz = xyz1[((long)b * N1 + n) * 3 + 2];
    float psq = __fadd_rn(__fadd_rn(__fmul_rn(px, px), __fmul_rn(py, py)), __fmul_rn(pz, pz));

    float b0 = 1e30f, b1 = 1e30f, b2 = 1e30f;
    int i0 = 0, i1 = 0, i2 = 0;

    for (int half = 0; half < 2; half++) {
        // stage this half of xyz2[b] with squared norm (ref formula, no FMA)
        for (int j = tid; j < N2 / 2; j += 512) {
            int jg = half * (N2 / 2) + j;
            float x = xyz2[((long)b * N2 + jg) * 3 + 0];
            float y = xyz2[((long)b * N2 + jg) * 3 + 1];
            float z = xyz2[((long)b * N2 + jg) * 3 + 2];
            float nsq = __fadd_rn(__fadd_rn(__fmul_rn(x, x), __fmul_rn(y, y)), __fmul_rn(z, z));
            pts[j] = make_float4(x, y, z, nsq);
        }
        __syncthreads();

        // scan this wave's 128-candidate slice (R3 body verbatim)
        int jbeg = half * (N2 / 2) + part * (N2 / 16);
        const float4* lp = &pts[part * (N2 / 16)];
#pragma unroll 8
        for (int jj = 0; jj < N2 / 16; jj++) {
            int j = jbeg + jj;
            float4 p = lp[jj];  // wave-uniform -> LDS broadcast
            float dot = __fadd_rn(__fadd_rn(__fmul_rn(px, p.x), __fmul_rn(py, p.y)),
                                  __fmul_rn(pz, p.z));
            float sq = __fsub_rn(__fadd_rn(psq, p.w), __fmul_rn(2.0f, dot));
            if (sq < b2) {
                if (sq < b1) {
                    b2 = b1; i2 = i1;
                    if (sq < b0) { b1 = b0; i1 = i0; b0 = sq; i0 = j; }
                    else         { b1 = sq; i1 = j; }
                } else { b2 = sq; i2 = j; }
            }
        }
        __syncthreads();  // scan done before half re-stage
    }

    // force the p1 values live here: loads must complete before this point,
    // i.e. they issue early and their latency hides under the scan above.
    asm volatile("" :: "v"(c0a.x), "v"(c0a.y), "v"(c0a.z), "v"(c0a.w),
                       "v"(c0b.x), "v"(c0b.y), "v"(c0b.z), "v"(c0b.w));
    asm volatile("" :: "v"(c1a.x), "v"(c1a.y), "v"(c1a.z), "v"(c1a.w),
                       "v"(c1b.x), "v"(c1b.y), "v"(c1b.z), "v"(c1b.w));

    m_d[part][ql][0] = b0; m_d[part][ql][1] = b1; m_d[part][ql][2] = b2;
    m_i[part][ql][0] = i0; m_i[part][ql][1] = i1; m_i[part][ql][2] = i2;
    __syncthreads();

    // ---- stage p1 tile into pts-alias (pts dead after scan) ----
    {
        unsigned* t32 = (unsigned*)pts;  // [64][64] u32: row = n-local, col = cp
        float r0[8] = {c0a.x, c0a.y, c0a.z, c0a.w, c0b.x, c0b.y, c0b.z, c0b.w};
        float r1[8] = {c1a.x, c1a.y, c1a.z, c1a.w, c1b.x, c1b.y, c1b.z, c1b.w};
#pragma unroll
        for (int k = 0; k < 8; k++) {
            unsigned v = (unsigned)f2bf(r0[k]) | ((unsigned)f2bf(r1[k]) << 16);
            t32[(g * 8 + k) * 64 + cp] = v;
        }
    }

    // merge 8x3 partials -> top-3, lexicographic (sq, idx). Parts scan
    // disjoint ranges so all 24 entries are distinct candidates.
    if (tid < 64) {
        float c0 = 1e30f, c1 = 1e30f, c2 = 1e30f;
        int a0 = 0x7fffffff, a1 = 0x7fffffff, a2 = 0x7fffffff;
#pragma unroll
        for (int pp = 0; pp < 8; pp++) {
#pragma unroll
            for (int k = 0; k < 3; k++) {
                float d = m_d[pp][tid][k];
                int ix = m_i[pp][tid][k];
                if (d < c2 || (d == c2 && ix < a2)) {
                    if (d < c1 || (d == c1 && ix < a1)) {
                        c2 = c1; a2 = a1;
                        if (d < c0 || (d == c0 && ix < a0)) { c1 = c0; a1 = a0; c0 = d; a0 = ix; }
                        else                                { c1 = d; a1 = ix; }
                    } else { c2 = d; a2 = ix; }
                }
            }
        }
        // exact reference math for winners: d = sqrt(max(sq,0)), clamp 1e-10
        float e0 = sqrtf(fmaxf(c0, 0.0f));
        float e1 = sqrtf(fmaxf(c1, 0.0f));
        float e2 = sqrtf(fmaxf(c2, 0.0f));
        float kd0 = fmaxf(e0, 1e-10f), kd1 = fmaxf(e1, 1e-10f), kd2 = fmaxf(e2, 1e-10f);
        float w0 = __fdiv_rn(1.0f, kd0), w1 = __fdiv_rn(1.0f, kd1), w2 = __fdiv_rn(1.0f, kd2);
        float wsum = __fadd_rn(__fadd_rn(w0, w1), w2);
        s_idx[tid][0] = a0; s_idx[tid][1] = a1; s_idx[tid][2] = a2;
        s_w[tid][0] = __fdiv_rn(w0, wsum);
        s_w[tid][1] = __fdiv_rn(w1, wsum);
        s_w[tid][2] = __fdiv_rn(w2, wsum);
    }
    __syncthreads();

    // ---- coalesced X[:,0:128] store: 32B/thread, 256B/row contiguous ----
    {
        const uint4* t128 = (const uint4*)pts;  // [64][16] uint4 per row
        int p = tid >> 3, ch = tid & 7;
        uint4 v0 = t128[p * 16 + ch * 2];
        uint4 v1 = t128[p * 16 + ch * 2 + 1];
        uint4* xo = (uint4*)(X + (long)(b * N1 + n0 + p) * 384);
        xo[ch * 2] = v0;
        xo[ch * 2 + 1] = v1;
    }

    // gather: wave w handles queries p = w, w+8, ...; lane l covers channels
    // [4l, 4l+4) as ushort4 (8 B/lane, coalesced 512 B/wave).
    int l = tid & 63;
    const u16* base = P2T + (long)b * N2 * C2;
#pragma unroll 2
    for (int p = part; p < 64; p += 8) {
        int j0 = s_idx[p][0], j1 = s_idx[p][1], j2 = s_idx[p][2];  // broadcast
        float f0 = s_w[p][0], f1 = s_w[p][1], f2 = s_w[p][2];
        ushort4 r0 = *(const ushort4*)&base[(long)j0 * C2 + l * 4];
        ushort4 r1 = *(const ushort4*)&base[(long)j1 * C2 + l * 4];
        ushort4 r2 = *(const ushort4*)&base[(long)j2 * C2 + l * 4];
        ushort4 o;
        o.x = f2bf(__fadd_rn(__fadd_rn(__fmul_rn(bf2f(r0.x), f0), __fmul_rn(bf2f(r1.x), f1)),
                             __fmul_rn(bf2f(r2.x), f2)));
        o.y = f2bf(__fadd_rn(__fadd_rn(__fmul_rn(bf2f(r0.y), f0), __fmul_rn(bf2f(r1.y), f1)),
                             __fmul_rn(bf2f(r2.y), f2)));
        o.z = f2bf(__fadd_rn(__fadd_rn(__fmul_rn(bf2f(r0.z), f0), __fmul_rn(bf2f(r1.z), f1)),
                             __fmul_rn(bf2f(r2.z), f2)));
        o.w = f2bf(__fadd_rn(__fadd_rn(__fmul_rn(bf2f(r0.w), f0), __fmul_rn(bf2f(r1.w), f1)),
                             __fmul_rn(bf2f(r2.w), f2)));
        *(ushort4*)&X[(long)(b * N1 + n0 + p) * 384 + 128 + l * 4] = o;
    }
}

// ---------------------------------------------------------------------------
// bf16 MFMA GEMM. R9 ASYNC path: BK=64 (two 32-K sub-tiles) per barrier pair.
// SWZ (R14, measured neutral, kept): pair col-tiles sharing an A row-tile on
// the same XCD. Non-ASYNC (gemm1): BK=32 VGPR staging + fused input BN+ReLU.
// Epilogue: bias add, bf16 store, per-channel sum/sumsq via atomics.
// ---------------------------------------------------------------------------
template <int KDIM, bool BN_IN, bool ASYNC, bool SWZ>
__global__ __launch_bounds__(256) void gemm_bn(const u16* __restrict__ A,
                                               const u16* __restrict__ Bw,
                                               const float* __restrict__ bias,
                                               const float* __restrict__ g_in_sum,
                                               const float* __restrict__ g_in_ssq,
                                               const float* __restrict__ gamma_in,
                                               const float* __restrict__ beta_in,
                                               u16* __restrict__ Yout, int Ntot,
                                               float* __restrict__ g_out_sum,
                                               float* __restrict__ g_out_ssq) {
    constexpr int LDSZ = ASYNC ? 2 * 128 * 32 : 128 * 40;  // u16 elems
    constexpr int SUB = 128 * 32;                          // sub-tile size (ASYNC)
    __shared__ __align__(16) u16 Al[LDSZ];
    __shared__ __align__(16) u16 Bl[LDSZ];
    __shared__ float s_stats[256];
    __shared__ float s_scale[BN_IN ? KDIM : 2];
    __shared__ float s_shift[BN_IN ? KDIM : 2];

    int tid = threadIdx.x;
    long s0;
    int o0;
    if constexpr (SWZ) {
        int bid = blockIdx.x;
        int xcd = bid & 7;
        int i = bid >> 3;               // 0..127 within XCD
        int u = xcd * 64 + (i >> 1);    // pair (row-tile) id 0..511
        s0 = (long)u * 128;
        o0 = (i & 1) * 128;
    } else {
        s0 = (long)blockIdx.y * 128;    // row tile
        o0 = blockIdx.x * 128;          // col tile
    }

    s_stats[tid] = 0.0f;
    if constexpr (BN_IN) {
        for (int k = tid; k < KDIM; k += 256) {
            float mu = g_in_sum[k] * (1.0f / 65536.0f);
            float var = g_in_ssq[k] * (1.0f / 65536.0f) - mu * mu;
            float rs = rsqrtf(var + 1e-5f);
            float sc = gamma_in[k] * rs;
            s_scale[k] = sc;
            s_shift[k] = beta_in[k] - mu * sc;
        }
    }
    int wid = tid >> 6, lane = tid & 63;
    int wm = wid >> 1, wn = wid & 1;
    int q = lane >> 4, l16 = lane & 15;

    f32x4 acc[4][4];
#pragma unroll
    for (int mi = 0; mi < 4; mi++)
#pragma unroll
        for (int ni = 0; ni < 4; ni++) acc[mi][ni] = (f32x4){0.f, 0.f, 0.f, 0.f};

    int rbase0 = wid * 32;
    int rsub = lane >> 2;
    int colsw = (((lane & 3) ^ (rsub & 3)) << 3);
    const u16* gA0 = A + (s0 + rbase0 + rsub) * KDIM + colsw;
    const u16* gA1 = gA0 + (long)16 * KDIM;
    const u16* gB0 = Bw + (long)(o0 + rbase0 + rsub) * KDIM + colsw;
    const u16* gB1 = gB0 + (long)16 * KDIM;
    u16* lA0 = &Al[rbase0 * 32];
    u16* lA1 = &Al[(rbase0 + 16) * 32];
    u16* lB0 = &Bl[rbase0 * 32];
    u16* lB1 = &Bl[(rbase0 + 16) * 32];
    int qA = ASYNC ? (q ^ (l16 & 3)) : q;

    __syncthreads();

    if constexpr (ASYNC) {
        for (int kt = 0; kt < KDIM; kt += 64) {
#pragma unroll
            for (int sub = 0; sub < 2; sub++) {
                int ko = kt + sub * 32;
                gl_lds16(gA0 + ko, lA0 + sub * SUB);
                gl_lds16(gA1 + ko, lA1 + sub * SUB);
                gl_lds16(gB0 + ko, lB0 + sub * SUB);
                gl_lds16(gB1 + ko, lB1 + sub * SUB);
            }
            __syncthreads();
#pragma unroll
            for (int sub = 0; sub < 2; sub++) {
                bf16x8 af[4], bfr[4];
#pragma unroll
                for (int mi = 0; mi < 4; mi++)
                    af[mi] = *(const bf16x8*)&Al[sub * SUB + (wm * 64 + mi * 16 + l16) * 32 + qA * 8];
#pragma unroll
                for (int ni = 0; ni < 4; ni++)
                    bfr[ni] = *(const bf16x8*)&Bl[sub * SUB + (wn * 64 + ni * 16 + l16) * 32 + qA * 8];
#pragma unroll
                for (int mi = 0; mi < 4; mi++)
#pragma unroll
                    for (int ni = 0; ni < 4; ni++)
                        acc[mi][ni] = __builtin_amdgcn_mfma_f32_16x16x32_bf16(af[mi], bfr[ni],
                                                                              acc[mi][ni], 0, 0, 0);
            }
            __syncthreads();
        }
    } else {
        for (int kt = 0; kt < KDIM; kt += 32) {
#pragma unroll
            for (int cc = 0; cc < 2; cc++) {
                int ci = tid + cc * 256;
                int row = ci >> 2;
                int kc = (ci & 3) << 3;
                union { uint4 u; u16 h[8]; } va;
                va.u = *(const uint4*)(A + (s0 + row) * KDIM + kt + kc);
                if constexpr (BN_IN) {
#pragma unroll
                    for (int j = 0; j < 8; j++) {
                        float f = bf2f(va.h[j]);
                        f = fmaxf(fmaf(f, s_scale[kt + kc + j], s_shift[kt + kc + j]), 0.0f);
                        va.h[j] = f2bf(f);
                    }
                }
                *(uint4*)&Al[row * 40 + kc] = va.u;
                *(uint4*)&Bl[row * 40 + kc] = *(const uint4*)(Bw + (long)(o0 + row) * KDIM + kt + kc);
            }
            __syncthreads();
            bf16x8 af[4], bfr[4];
#pragma unroll
            for (int mi = 0; mi < 4; mi++)
                af[mi] = *(const bf16x8*)&Al[(wm * 64 + mi * 16 + l16) * 40 + qA * 8];
#pragma unroll
            for (int ni = 0; ni < 4; ni++)
                bfr[ni] = *(const bf16x8*)&Bl[(wn * 64 + ni * 16 + l16) * 40 + qA * 8];
#pragma unroll
            for (int mi = 0; mi < 4; mi++)
#pragma unroll
                for (int ni = 0; ni < 4; ni++)
                    acc[mi][ni] = __builtin_amdgcn_mfma_f32_16x16x32_bf16(af[mi], bfr[ni],
                                                                          acc[mi][ni], 0, 0, 0);
            __syncthreads();
        }
    }

#pragma unroll
    for (int ni = 0; ni < 4; ni++) {
        int coll = wn * 64 + ni * 16 + l16;
        int col = o0 + coll;
        float bz = bias[col];
        float s1 = 0.0f, s2 = 0.0f;
#pragma unroll
        for (int mi = 0; mi < 4; mi++) {
#pragma unroll
            for (int r = 0; r < 4; r++) {
                float v = acc[mi][ni][r] + bz;
                s1 += v;
                s2 += v * v;
                long row = s0 + wm * 64 + mi * 16 + q * 4 + r;
                Yout[row * Ntot + col] = f2bf(v);
            }
        }
        s1 += __shfl_xor(s1, 16, 64);
        s1 += __shfl_xor(s1, 32, 64);
        s2 += __shfl_xor(s2, 16, 64);
        s2 += __shfl_xor(s2, 32, 64);
        if (q == 0) {
            atomicAdd(&s_stats[coll], s1);
            atomicAdd(&s_stats[128 + coll], s2);
        }
    }
    __syncthreads();
    if (tid < 128) {
        atomicAdd(&g_out_sum[o0 + tid], s_stats[tid]);
        atomicAdd(&g_out_ssq[o0 + tid], s_stats[128 + tid]);
    }
}

// ---------------------------------------------------------------------------
// final BN+ReLU + transpose to [B][128][N1] fp32 (Y1 bf16, 16B reads)
// ---------------------------------------------------------------------------
__global__ __launch_bounds__(256) void finalize_k(const u16* __restrict__ Y1,
                                                  const float* __restrict__ g_sum,
                                                  const float* __restrict__ g_ssq,
                                                  const float* __restrict__ gamma,
                                                  const float* __restrict__ beta,
                                                  float* __restrict__ out) {
    __shared__ float s_scale[128], s_shift[128];
    int tid = threadIdx.x;
    if (tid < 128) {
        float mu = g_sum[tid] * (1.0f / 65536.0f);
        float var = g_ssq[tid] * (1.0f / 65536.0f) - mu * mu;
        float rs = rsqrtf(var + 1e-5f);
        float sc = gamma[tid] * rs;
        s_scale[tid] = sc;
        s_shift[tid] = beta[tid] - mu * sc;
    }
    __syncthreads();
    long s = (long)blockIdx.x * 256 + tid;
    int b = (int)(s >> 13);
    int n = (int)(s & 8191);
    const u16* yrow = Y1 + s * 128;
    float* obase = out + (long)b * 128 * 8192 + n;
#pragma unroll
    for (int oc = 0; oc < 128; oc += 8) {
        union { uint4 u; u16 h[8]; } va;
        va.u = *(const uint4*)&yrow[oc];
#pragma unroll
        for (int k = 0; k < 8; k++) {
            int o = oc + k;
            float v = fmaxf(fmaf(bf2f(va.h[k]), s_scale[o], s_shift[o]), 0.0f);
            obase[(long)o * 8192] = v;
        }
    }
}

// ---------------------------------------------------------------------------
// launch (5 dispatches)
// ---------------------------------------------------------------------------
extern "C" void kernel_launch(void* const* d_in, const int* in_sizes, int n_in,
                              void* d_out, int out_size, void* d_ws, size_t ws_size,
                              hipStream_t stream) {
    const float* xyz1    = (const float*)d_in[0];
    const float* xyz2    = (const float*)d_in[1];
    const float* points1 = (const float*)d_in[2];
    const float* points2 = (const float*)d_in[3];
    const float* w0 = (const float*)d_in[4];
    const float* b0 = (const float*)d_in[5];
    const float* gamma0 = (const float*)d_in[6];
    const float* beta0 = (const float*)d_in[7];
    const float* w1 = (const float*)d_in[8];
    const float* b1 = (const float*)d_in[9];
    const float* gamma1 = (const float*)d_in[10];
    const float* beta1 = (const float*)d_in[11];
    float* out = (float*)d_out;

    char* ws = (char*)d_ws;
    u16* X       = (u16*)(ws + 0);             // 65536 x 384 bf16 = 50,331,648
    u16* P2T     = (u16*)(ws + 50331648);      // 8,388,608
    u16* w0b     = (u16*)(ws + 58720256);      // 196,608
    u16* w1b     = (u16*)(ws + 58916864);      // 65,536
    u16* Y0      = (u16*)(ws + 58982400);      // 33,554,432
    u16* Y1b     = (u16*)(ws + 92536832);      // 16,777,216
    float* stats = (float*)(ws + 109314048);   // 3,072
    if (ws_size < 109317120) return;
    float* gsum0 = stats;
    float* gss0  = stats + 256;
    float* gsum1 = stats + 512;
    float* gss1  = stats + 640;

    preproc<<<4609, 256, 0, stream>>>(w0, w1, points2, w0b, w1b, P2T, stats);
    knn_interp<<<dim3(128, 8), 512, 0, stream>>>(xyz1, xyz2, points1, P2T, X);
    gemm_bn<384, false, true, true><<<1024, 256, 0, stream>>>(
        X, w0b, b0, nullptr, nullptr, nullptr, nullptr, Y0, 256, gsum0, gss0);
    gemm_bn<256, true, false, false><<<dim3(1, 512), 256, 0, stream>>>(
        Y0, w1b, b1, gsum0, gss0, gamma0, beta0, Y1b, 128, gsum1, gss1);
    finalize_k<<<256, 256, 0, stream>>>(Y1b, gsum1, gss1, gamma1, beta1, out);
}

// Round 8
// 242.948 us; speedup vs baseline: 1.0054x; 1.0054x over previous
//
#include <hip/hip_runtime.h>
#include <cstdint>

using u16 = unsigned short;
typedef short bf16x8 __attribute__((ext_vector_type(8)));
typedef float f32x4 __attribute__((ext_vector_type(4)));

__device__ __forceinline__ float bf2f(u16 h) {
    union { unsigned u; float f; } x;
    x.u = ((unsigned)h) << 16;
    return x.f;
}
__device__ __forceinline__ u16 f2bf(float f) {
    union { float f; unsigned u; } x;
    x.f = f;
    unsigned r = x.u + 0x7fffu + ((x.u >> 16) & 1u);
    return (u16)(r >> 16);
}

// async global->LDS, 16B per lane; LDS dest is wave-uniform base + lane*16
__device__ __forceinline__ void gl_lds16(const u16* g, u16* l) {
    __builtin_amdgcn_global_load_lds((const __attribute__((address_space(1))) void*)g,
                                     (__attribute__((address_space(3))) void*)l, 16, 0, 0);
}

#define N1 8192
#define N2 2048
#define C2 256

// ---------------------------------------------------------------------------
// preproc (R15): points2 transpose + w0/w1 cvt + stats zero.
// ---------------------------------------------------------------------------
__device__ __forceinline__ void tr_tile(const float* __restrict__ src,
                                        u16* __restrict__ dst,
                                        int C, int N, int ds, int b, int n0, int c0,
                                        int tid, float (*tile)[33]) {
    int tx = tid & 31, ty = tid >> 5;  // 32 x 8
    const float* s = src + (long)b * C * N;
#pragma unroll
    for (int i = 0; i < 4; i++) {
        int c = ty + i * 8;
        tile[c][tx] = s[(long)(c0 + c) * N + n0 + tx];
    }
    __syncthreads();
    u16* d = dst + (long)b * N * ds;
#pragma unroll
    for (int i = 0; i < 4; i++) {
        int n = ty + i * 8;
        d[(long)(n0 + n) * ds + c0 + tx] = f2bf(tile[tx][n]);
    }
}

__global__ __launch_bounds__(256) void preproc(const float* __restrict__ w0,
                                               const float* __restrict__ w1,
                                               const float* __restrict__ points2,
                                               u16* __restrict__ w0b,
                                               u16* __restrict__ w1b,
                                               u16* __restrict__ P2T,
                                               float* __restrict__ stats) {
    __shared__ float tile[32][33];
    int bid = blockIdx.x, tid = threadIdx.x;
    if (bid < 4096) {
        int nb = bid & 63, cb = (bid >> 6) & 7, b = bid >> 9;
        tr_tile(points2, P2T, 256, 2048, 256, b, nb * 32, cb * 32, tid, tile);
    } else if (bid < 4480) {
        int i = (bid - 4096) * 256 + tid;
        w0b[i] = f2bf(w0[i]);
    } else if (bid < 4608) {
        int i = (bid - 4480) * 256 + tid;
        w1b[i] = f2bf(w1[i]);
    } else {
        for (int i = tid; i < 768; i += 256) stats[i] = 0.0f;
    }
}

// ---------------------------------------------------------------------------
// kNN(3) + interpolation — R17: scan/merge/gather = R9 VERBATIM (frozen).
// Fused points1->X copy, v3. R16 post-mortem: (a) VGPR=24 proved the value
// asm-keep did NOT pin load issue — compiler sank the loads to just before
// the keep. Fix: `asm volatile("" ::: "memory")` right AFTER the loads: a
// load can't move down past a potential memory writer, so issue is pinned
// before the scan and the waitcnt lands at first use (~70us later).
// (b) 983K bank conflicts: staging row stride 64 u32 = 0 mod 32 banks with
// only 8 distinct cols/wave -> 8-way. Fix: pad stride to 65 u32 -> bank =
// (row+col) mod 32 -> exact 2-way (free, m136). Pad breaks 16B alignment so
// the read side is 8x ds_read_b32 (also 2-way) -> two uint4 global stores
// (coalescing unchanged: 32B/thread, 256B/row).
// ---------------------------------------------------------------------------
__global__ __launch_bounds__(512) void knn_interp(const float* __restrict__ xyz1,
                                                  const float* __restrict__ xyz2,
                                                  const float* __restrict__ points1,
                                                  const u16* __restrict__ P2T,  // [B][N2][C2]
                                                  u16* __restrict__ X) {       // [B*N1][384]
    __shared__ float4 pts[N2 / 2 + 16];  // 16640 B (scan stage; reused as p1 tile, stride-65)
    __shared__ float m_d[8][64][3];      // 6144 B partial top-3 (squared dist)
    __shared__ int   m_i[8][64][3];      // 6144 B
    __shared__ int   s_idx[64][3];
    __shared__ float s_w[64][3];
    int b = blockIdx.y;
    int n0 = blockIdx.x * 64;
    int tid = threadIdx.x;
    int ql = tid & 63;       // query within block
    int part = tid >> 6;     // candidate partition 0..7 (== wave id)

    // ---- fused points1 copy: issue loads NOW; memory clobber pins them
    // here (can't sink past a potential memory writer) -> latency hides
    // under the VALU-bound scan; waitcnt lands at the staging below.
    int cp = tid >> 3;       // channel pair: channels 2cp, 2cp+1
    int g = tid & 7;         // n-octet within the 64-query tile
    const float* p1r0 = points1 + ((long)b * 128 + 2 * cp) * N1 + n0 + g * 8;
    const float* p1r1 = p1r0 + N1;
    float4 c0a = *(const float4*)(p1r0);
    float4 c0b = *(const float4*)(p1r0 + 4);
    float4 c1a = *(const float4*)(p1r1);
    float4 c1b = *(const float4*)(p1r1 + 4);
    asm volatile("" ::: "memory");

    int n = n0 + ql;
    float px = xyz1[((long)b * N1 + n) * 3 + 0];
    float py = xyz1[((long)b * N1 + n) * 3 + 1];
    float pz = xyz1[((long)b * N1 + n) * 3 + 2];
    float psq = __fadd_rn(__fadd_rn(__fmul_rn(px, px), __fmul_rn(py, py)), __fmul_rn(pz, pz));

    float b0 = 1e30f, b1 = 1e30f, b2 = 1e30f;
    int i0 = 0, i1 = 0, i2 = 0;

    for (int half = 0; half < 2; half++) {
        // stage this half of xyz2[b] with squared norm (ref formula, no FMA)
        for (int j = tid; j < N2 / 2; j += 512) {
            int jg = half * (N2 / 2) + j;
            float x = xyz2[((long)b * N2 + jg) * 3 + 0];
            float y = xyz2[((long)b * N2 + jg) * 3 + 1];
            float z = xyz2[((long)b * N2 + jg) * 3 + 2];
            float nsq = __fadd_rn(__fadd_rn(__fmul_rn(x, x), __fmul_rn(y, y)), __fmul_rn(z, z));
            pts[j] = make_float4(x, y, z, nsq);
        }
        __syncthreads();

        // scan this wave's 128-candidate slice (R3 body verbatim)
        int jbeg = half * (N2 / 2) + part * (N2 / 16);
        const float4* lp = &pts[part * (N2 / 16)];
#pragma unroll 8
        for (int jj = 0; jj < N2 / 16; jj++) {
            int j = jbeg + jj;
            float4 p = lp[jj];  // wave-uniform -> LDS broadcast
            float dot = __fadd_rn(__fadd_rn(__fmul_rn(px, p.x), __fmul_rn(py, p.y)),
                                  __fmul_rn(pz, p.z));
            float sq = __fsub_rn(__fadd_rn(psq, p.w), __fmul_rn(2.0f, dot));
            if (sq < b2) {
                if (sq < b1) {
                    b2 = b1; i2 = i1;
                    if (sq < b0) { b1 = b0; i1 = i0; b0 = sq; i0 = j; }
                    else         { b1 = sq; i1 = j; }
                } else { b2 = sq; i2 = j; }
            }
        }
        __syncthreads();  // scan done before half re-stage
    }

    m_d[part][ql][0] = b0; m_d[part][ql][1] = b1; m_d[part][ql][2] = b2;
    m_i[part][ql][0] = i0; m_i[part][ql][1] = i1; m_i[part][ql][2] = i2;
    __syncthreads();

    // ---- stage p1 tile into pts-alias (dead after scan), stride 65 u32 ----
    {
        unsigned* t32 = (unsigned*)pts;  // [64] rows x stride-65 u32, col = cp
        float r0[8] = {c0a.x, c0a.y, c0a.z, c0a.w, c0b.x, c0b.y, c0b.z, c0b.w};
        float r1[8] = {c1a.x, c1a.y, c1a.z, c1a.w, c1b.x, c1b.y, c1b.z, c1b.w};
#pragma unroll
        for (int k = 0; k < 8; k++) {
            unsigned v = (unsigned)f2bf(r0[k]) | ((unsigned)f2bf(r1[k]) << 16);
            t32[(g * 8 + k) * 65 + cp] = v;
        }
    }

    // merge 8x3 partials -> top-3, lexicographic (sq, idx). Parts scan
    // disjoint ranges so all 24 entries are distinct candidates.
    if (tid < 64) {
        float c0 = 1e30f, c1 = 1e30f, c2 = 1e30f;
        int a0 = 0x7fffffff, a1 = 0x7fffffff, a2 = 0x7fffffff;
#pragma unroll
        for (int pp = 0; pp < 8; pp++) {
#pragma unroll
            for (int k = 0; k < 3; k++) {
                float d = m_d[pp][tid][k];
                int ix = m_i[pp][tid][k];
                if (d < c2 || (d == c2 && ix < a2)) {
                    if (d < c1 || (d == c1 && ix < a1)) {
                        c2 = c1; a2 = a1;
                        if (d < c0 || (d == c0 && ix < a0)) { c1 = c0; a1 = a0; c0 = d; a0 = ix; }
                        else                                { c1 = d; a1 = ix; }
                    } else { c2 = d; a2 = ix; }
                }
            }
        }
        // exact reference math for winners: d = sqrt(max(sq,0)), clamp 1e-10
        float e0 = sqrtf(fmaxf(c0, 0.0f));
        float e1 = sqrtf(fmaxf(c1, 0.0f));
        float e2 = sqrtf(fmaxf(c2, 0.0f));
        float kd0 = fmaxf(e0, 1e-10f), kd1 = fmaxf(e1, 1e-10f), kd2 = fmaxf(e2, 1e-10f);
        float w0 = __fdiv_rn(1.0f, kd0), w1 = __fdiv_rn(1.0f, kd1), w2 = __fdiv_rn(1.0f, kd2);
        float wsum = __fadd_rn(__fadd_rn(w0, w1), w2);
        s_idx[tid][0] = a0; s_idx[tid][1] = a1; s_idx[tid][2] = a2;
        s_w[tid][0] = __fdiv_rn(w0, wsum);
        s_w[tid][1] = __fdiv_rn(w1, wsum);
        s_w[tid][2] = __fdiv_rn(w2, wsum);
    }
    __syncthreads();

    // ---- coalesced X[:,0:128] store: 8x ds_read_b32 (2-way, free) ->
    // two uint4 stores = 32B/thread, 256B/row contiguous ----
    {
        const unsigned* t32 = (const unsigned*)pts;
        int p = tid >> 3, ch = tid & 7;
        unsigned v[8];
#pragma unroll
        for (int j = 0; j < 8; j++) v[j] = t32[p * 65 + ch * 8 + j];
        uint4* xo = (uint4*)(X + (long)(b * N1 + n0 + p) * 384);
        xo[ch * 2]     = make_uint4(v[0], v[1], v[2], v[3]);
        xo[ch * 2 + 1] = make_uint4(v[4], v[5], v[6], v[7]);
    }

    // gather: wave w handles queries p = w, w+8, ...; lane l covers channels
    // [4l, 4l+4) as ushort4 (8 B/lane, coalesced 512 B/wave).
    int l = tid & 63;
    const u16* base = P2T + (long)b * N2 * C2;
#pragma unroll 2
    for (int p = part; p < 64; p += 8) {
        int j0 = s_idx[p][0], j1 = s_idx[p][1], j2 = s_idx[p][2];  // broadcast
        float f0 = s_w[p][0], f1 = s_w[p][1], f2 = s_w[p][2];
        ushort4 r0 = *(const ushort4*)&base[(long)j0 * C2 + l * 4];
        ushort4 r1 = *(const ushort4*)&base[(long)j1 * C2 + l * 4];
        ushort4 r2 = *(const ushort4*)&base[(long)j2 * C2 + l * 4];
        ushort4 o;
        o.x = f2bf(__fadd_rn(__fadd_rn(__fmul_rn(bf2f(r0.x), f0), __fmul_rn(bf2f(r1.x), f1)),
                             __fmul_rn(bf2f(r2.x), f2)));
        o.y = f2bf(__fadd_rn(__fadd_rn(__fmul_rn(bf2f(r0.y), f0), __fmul_rn(bf2f(r1.y), f1)),
                             __fmul_rn(bf2f(r2.y), f2)));
        o.z = f2bf(__fadd_rn(__fadd_rn(__fmul_rn(bf2f(r0.z), f0), __fmul_rn(bf2f(r1.z), f1)),
                             __fmul_rn(bf2f(r2.z), f2)));
        o.w = f2bf(__fadd_rn(__fadd_rn(__fmul_rn(bf2f(r0.w), f0), __fmul_rn(bf2f(r1.w), f1)),
                             __fmul_rn(bf2f(r2.w), f2)));
        *(ushort4*)&X[(long)(b * N1 + n0 + p) * 384 + 128 + l * 4] = o;
    }
}

// ---------------------------------------------------------------------------
// bf16 MFMA GEMM. R9 ASYNC path: BK=64 (two 32-K sub-tiles) per barrier pair.
// SWZ (R14, measured neutral, kept): pair col-tiles sharing an A row-tile on
// the same XCD. Non-ASYNC (gemm1): BK=32 VGPR staging + fused input BN+ReLU.
// Epilogue: bias add, bf16 store, per-channel sum/sumsq via atomics.
// ---------------------------------------------------------------------------
template <int KDIM, bool BN_IN, bool ASYNC, bool SWZ>
__global__ __launch_bounds__(256) void gemm_bn(const u16* __restrict__ A,
                                               const u16* __restrict__ Bw,
                                               const float* __restrict__ bias,
                                               const float* __restrict__ g_in_sum,
                                               const float* __restrict__ g_in_ssq,
                                               const float* __restrict__ gamma_in,
                                               const float* __restrict__ beta_in,
                                               u16* __restrict__ Yout, int Ntot,
                                               float* __restrict__ g_out_sum,
                                               float* __restrict__ g_out_ssq) {
    constexpr int LDSZ = ASYNC ? 2 * 128 * 32 : 128 * 40;  // u16 elems
    constexpr int SUB = 128 * 32;                          // sub-tile size (ASYNC)
    __shared__ __align__(16) u16 Al[LDSZ];
    __shared__ __align__(16) u16 Bl[LDSZ];
    __shared__ float s_stats[256];
    __shared__ float s_scale[BN_IN ? KDIM : 2];
    __shared__ float s_shift[BN_IN ? KDIM : 2];

    int tid = threadIdx.x;
    long s0;
    int o0;
    if constexpr (SWZ) {
        int bid = blockIdx.x;
        int xcd = bid & 7;
        int i = bid >> 3;               // 0..127 within XCD
        int u = xcd * 64 + (i >> 1);    // pair (row-tile) id 0..511
        s0 = (long)u * 128;
        o0 = (i & 1) * 128;
    } else {
        s0 = (long)blockIdx.y * 128;    // row tile
        o0 = blockIdx.x * 128;          // col tile
    }

    s_stats[tid] = 0.0f;
    if constexpr (BN_IN) {
        for (int k = tid; k < KDIM; k += 256) {
            float mu = g_in_sum[k] * (1.0f / 65536.0f);
            float var = g_in_ssq[k] * (1.0f / 65536.0f) - mu * mu;
            float rs = rsqrtf(var + 1e-5f);
            float sc = gamma_in[k] * rs;
            s_scale[k] = sc;
            s_shift[k] = beta_in[k] - mu * sc;
        }
    }
    int wid = tid >> 6, lane = tid & 63;
    int wm = wid >> 1, wn = wid & 1;
    int q = lane >> 4, l16 = lane & 15;

    f32x4 acc[4][4];
#pragma unroll
    for (int mi = 0; mi < 4; mi++)
#pragma unroll
        for (int ni = 0; ni < 4; ni++) acc[mi][ni] = (f32x4){0.f, 0.f, 0.f, 0.f};

    int rbase0 = wid * 32;
    int rsub = lane >> 2;
    int colsw = (((lane & 3) ^ (rsub & 3)) << 3);
    const u16* gA0 = A + (s0 + rbase0 + rsub) * KDIM + colsw;
    const u16* gA1 = gA0 + (long)16 * KDIM;
    const u16* gB0 = Bw + (long)(o0 + rbase0 + rsub) * KDIM + colsw;
    const u16* gB1 = gB0 + (long)16 * KDIM;
    u16* lA0 = &Al[rbase0 * 32];
    u16* lA1 = &Al[(rbase0 + 16) * 32];
    u16* lB0 = &Bl[rbase0 * 32];
    u16* lB1 = &Bl[(rbase0 + 16) * 32];
    int qA = ASYNC ? (q ^ (l16 & 3)) : q;

    __syncthreads();

    if constexpr (ASYNC) {
        for (int kt = 0; kt < KDIM; kt += 64) {
#pragma unroll
            for (int sub = 0; sub < 2; sub++) {
                int ko = kt + sub * 32;
                gl_lds16(gA0 + ko, lA0 + sub * SUB);
                gl_lds16(gA1 + ko, lA1 + sub * SUB);
                gl_lds16(gB0 + ko, lB0 + sub * SUB);
                gl_lds16(gB1 + ko, lB1 + sub * SUB);
            }
            __syncthreads();
#pragma unroll
            for (int sub = 0; sub < 2; sub++) {
                bf16x8 af[4], bfr[4];
#pragma unroll
                for (int mi = 0; mi < 4; mi++)
                    af[mi] = *(const bf16x8*)&Al[sub * SUB + (wm * 64 + mi * 16 + l16) * 32 + qA * 8];
#pragma unroll
                for (int ni = 0; ni < 4; ni++)
                    bfr[ni] = *(const bf16x8*)&Bl[sub * SUB + (wn * 64 + ni * 16 + l16) * 32 + qA * 8];
#pragma unroll
                for (int mi = 0; mi < 4; mi++)
#pragma unroll
                    for (int ni = 0; ni < 4; ni++)
                        acc[mi][ni] = __builtin_amdgcn_mfma_f32_16x16x32_bf16(af[mi], bfr[ni],
                                                                              acc[mi][ni], 0, 0, 0);
            }
            __syncthreads();
        }
    } else {
        for (int kt = 0; kt < KDIM; kt += 32) {
#pragma unroll
            for (int cc = 0; cc < 2; cc++) {
                int ci = tid + cc * 256;
                int row = ci >> 2;
                int kc = (ci & 3) << 3;
                union { uint4 u; u16 h[8]; } va;
                va.u = *(const uint4*)(A + (s0 + row) * KDIM + kt + kc);
                if constexpr (BN_IN) {
#pragma unroll
                    for (int j = 0; j < 8; j++) {
                        float f = bf2f(va.h[j]);
                        f = fmaxf(fmaf(f, s_scale[kt + kc + j], s_shift[kt + kc + j]), 0.0f);
                        va.h[j] = f2bf(f);
                    }
                }
                *(uint4*)&Al[row * 40 + kc] = va.u;
                *(uint4*)&Bl[row * 40 + kc] = *(const uint4*)(Bw + (long)(o0 + row) * KDIM + kt + kc);
            }
            __syncthreads();
            bf16x8 af[4], bfr[4];
#pragma unroll
            for (int mi = 0; mi < 4; mi++)
                af[mi] = *(const bf16x8*)&Al[(wm * 64 + mi * 16 + l16) * 40 + qA * 8];
#pragma unroll
            for (int ni = 0; ni < 4; ni++)
                bfr[ni] = *(const bf16x8*)&Bl[(wn * 64 + ni * 16 + l16) * 40 + qA * 8];
#pragma unroll
            for (int mi = 0; mi < 4; mi++)
#pragma unroll
                for (int ni = 0; ni < 4; ni++)
                    acc[mi][ni] = __builtin_amdgcn_mfma_f32_16x16x32_bf16(af[mi], bfr[ni],
                                                                          acc[mi][ni], 0, 0, 0);
            __syncthreads();
        }
    }

#pragma unroll
    for (int ni = 0; ni < 4; ni++) {
        int coll = wn * 64 + ni * 16 + l16;
        int col = o0 + coll;
        float bz = bias[col];
        float s1 = 0.0f, s2 = 0.0f;
#pragma unroll
        for (int mi = 0; mi < 4; mi++) {
#pragma unroll
            for (int r = 0; r < 4; r++) {
                float v = acc[mi][ni][r] + bz;
                s1 += v;
                s2 += v * v;
                long row = s0 + wm * 64 + mi * 16 + q * 4 + r;
                Yout[row * Ntot + col] = f2bf(v);
            }
        }
        s1 += __shfl_xor(s1, 16, 64);
        s1 += __shfl_xor(s1, 32, 64);
        s2 += __shfl_xor(s2, 16, 64);
        s2 += __shfl_xor(s2, 32, 64);
        if (q == 0) {
            atomicAdd(&s_stats[coll], s1);
            atomicAdd(&s_stats[128 + coll], s2);
        }
    }
    __syncthreads();
    if (tid < 128) {
        atomicAdd(&g_out_sum[o0 + tid], s_stats[tid]);
        atomicAdd(&g_out_ssq[o0 + tid], s_stats[128 + tid]);
    }
}

// ---------------------------------------------------------------------------
// final BN+ReLU + transpose to [B][128][N1] fp32 (Y1 bf16, 16B reads)
// ---------------------------------------------------------------------------
__global__ __launch_bounds__(256) void finalize_k(const u16* __restrict__ Y1,
                                                  const float* __restrict__ g_sum,
                                                  const float* __restrict__ g_ssq,
                                                  const float* __restrict__ gamma,
                                                  const float* __restrict__ beta,
                                                  float* __restrict__ out) {
    __shared__ float s_scale[128], s_shift[128];
    int tid = threadIdx.x;
    if (tid < 128) {
        float mu = g_sum[tid] * (1.0f / 65536.0f);
        float var = g_ssq[tid] * (1.0f / 65536.0f) - mu * mu;
        float rs = rsqrtf(var + 1e-5f);
        float sc = gamma[tid] * rs;
        s_scale[tid] = sc;
        s_shift[tid] = beta[tid] - mu * sc;
    }
    __syncthreads();
    long s = (long)blockIdx.x * 256 + tid;
    int b = (int)(s >> 13);
    int n = (int)(s & 8191);
    const u16* yrow = Y1 + s * 128;
    float* obase = out + (long)b * 128 * 8192 + n;
#pragma unroll
    for (int oc = 0; oc < 128; oc += 8) {
        union { uint4 u; u16 h[8]; } va;
        va.u = *(const uint4*)&yrow[oc];
#pragma unroll
        for (int k = 0; k < 8; k++) {
            int o = oc + k;
            float v = fmaxf(fmaf(bf2f(va.h[k]), s_scale[o], s_shift[o]), 0.0f);
            obase[(long)o * 8192] = v;
        }
    }
}

// ---------------------------------------------------------------------------
// launch (5 dispatches)
// ---------------------------------------------------------------------------
extern "C" void kernel_launch(void* const* d_in, const int* in_sizes, int n_in,
                              void* d_out, int out_size, void* d_ws, size_t ws_size,
                              hipStream_t stream) {
    const float* xyz1    = (const float*)d_in[0];
    const float* xyz2    = (const float*)d_in[1];
    const float* points1 = (const float*)d_in[2];
    const float* points2 = (const float*)d_in[3];
    const float* w0 = (const float*)d_in[4];
    const float* b0 = (const float*)d_in[5];
    const float* gamma0 = (const float*)d_in[6];
    const float* beta0 = (const float*)d_in[7];
    const float* w1 = (const float*)d_in[8];
    const float* b1 = (const float*)d_in[9];
    const float* gamma1 = (const float*)d_in[10];
    const float* beta1 = (const float*)d_in[11];
    float* out = (float*)d_out;

    char* ws = (char*)d_ws;
    u16* X       = (u16*)(ws + 0);             // 65536 x 384 bf16 = 50,331,648
    u16* P2T     = (u16*)(ws + 50331648);      // 8,388,608
    u16* w0b     = (u16*)(ws + 58720256);      // 196,608
    u16* w1b     = (u16*)(ws + 58916864);      // 65,536
    u16* Y0      = (u16*)(ws + 58982400);      // 33,554,432
    u16* Y1b     = (u16*)(ws + 92536832);      // 16,777,216
    float* stats = (float*)(ws + 109314048);   // 3,072
    if (ws_size < 109317120) return;
    float* gsum0 = stats;
    float* gss0  = stats + 256;
    float* gsum1 = stats + 512;
    float* gss1  = stats + 640;

    preproc<<<4609, 256, 0, stream>>>(w0, w1, points2, w0b, w1b, P2T, stats);
    knn_interp<<<dim3(128, 8), 512, 0, stream>>>(xyz1, xyz2, points1, P2T, X);
    gemm_bn<384, false, true, true><<<1024, 256, 0, stream>>>(
        X, w0b, b0, nullptr, nullptr, nullptr, nullptr, Y0, 256, gsum0, gss0);
    gemm_bn<256, true, false, false><<<dim3(1, 512), 256, 0, stream>>>(
        Y0, w1b, b1, gsum0, gss0, gamma0, beta0, Y1b, 128, gsum1, gss1);
    finalize_k<<<256, 256, 0, stream>>>(Y1b, gsum1, gss1, gamma1, beta1, out);
}